// Round 4
// baseline (774.057 us; speedup 1.0000x reference)
//
#include <hip/hip_runtime.h>
#include <math.h>

#define N_NODES 100000
#define N_EDGES 1600000
#define HIDDEN 128

// du-accumulation kernel geometry
#define NBLK  64              // blocks; each owns ceil(N/NBLK) nodes
#define NPB   1563            // nodes per block (64*1563 = 100032 >= 100000)
#define NTHR  1024            // 16 waves
#define NWAVE (NTHR / 64)
#define QCAP  128             // per-wave ring-queue entries (power of 2)

// Native 4-wide float vector — required for __builtin_nontemporal_store.
typedef float vfloat4 __attribute__((ext_vector_type(4)));

// ---------------------------------------------------------------------------
// Dense processing of one queued edge: unit vector + LDS accumulate.
// ---------------------------------------------------------------------------
__device__ __forceinline__ void process_edge(
    unsigned r, unsigned c, unsigned base, unsigned nloc,
    const float* __restrict__ pos, float* __restrict__ acc)
{
    float rx = pos[r * 3 + 0], ry = pos[r * 3 + 1], rz = pos[r * 3 + 2];
    float cx = pos[c * 3 + 0], cy = pos[c * 3 + 1], cz = pos[c * 3 + 2];
    float dx = cx - rx, dy = cy - ry, dz = cz - rz;
    float inv = 1.0f / (sqrtf(dx * dx + dy * dy + dz * dz) + 1e-8f);
    float ux = dx * inv, uy = dy * inv, uz = dz * inv;

    unsigned rl = r - base, cl = c - base;
    if (rl < nloc) {
        atomicAdd(&acc[rl * 3 + 0],  ux);
        atomicAdd(&acc[rl * 3 + 1],  uy);
        atomicAdd(&acc[rl * 3 + 2],  uz);
    }
    if (cl < nloc) {
        atomicAdd(&acc[cl * 3 + 0], -ux);
        atomicAdd(&acc[cl * 3 + 1], -uy);
        atomicAdd(&acc[cl * 3 + 2], -uz);
    }
}

// ---------------------------------------------------------------------------
// Kernel 1: block-owned node ranges, NO global atomics.
// Each block scans all edges (eidx is L3-hot), ballot-compacts in-range edges
// into a wave-private LDS ring queue, drains 64-dense, accumulates du in LDS,
// then writes its du slice once, coalesced.
// ---------------------------------------------------------------------------
__global__ __launch_bounds__(NTHR) void du_range_kernel(
    const float* __restrict__ pos, const int* __restrict__ eidx,
    float* __restrict__ du)
{
    __shared__ float acc[NPB * 3];          // 18,756 B
    __shared__ uint2 q[NWAVE * QCAP];       // 16,384 B

    const unsigned base = blockIdx.x * NPB;
    const unsigned nloc = min((unsigned)NPB, (unsigned)(N_NODES - base));

    for (int i = threadIdx.x; i < NPB * 3; i += NTHR) acc[i] = 0.0f;
    __syncthreads();

    const int lane = threadIdx.x & 63;
    uint2* wq = q + (threadIdx.x >> 6) * QCAP;
    unsigned qhead = 0;   // ring read index (wave-uniform)
    unsigned qn    = 0;   // pending entries  (wave-uniform)

    // N_EDGES % 64 == 0 and stride is 1024, so every wave executes each
    // iteration with all 64 lanes active (ballot is always full-wave).
    for (int e = threadIdx.x; e < N_EDGES; e += NTHR) {
        unsigned r = (unsigned)eidx[e];
        unsigned c = (unsigned)eidx[N_EDGES + e];
        bool hit = ((r - base) < nloc) || ((c - base) < nloc);
        unsigned long long m = __ballot(hit);
        if (hit) {
            unsigned pre = __popcll(m & ((1ull << lane) - 1ull));
            wq[(qhead + qn + pre) & (QCAP - 1)] = make_uint2(r, c);
        }
        qn += (unsigned)__popcll(m);
        if (qn >= 64) {
            __builtin_amdgcn_wave_barrier();   // order ds_write -> ds_read
            uint2 rc = wq[(qhead + lane) & (QCAP - 1)];
            process_edge(rc.x, rc.y, base, nloc, pos, acc);
            qhead += 64; qn -= 64;
        }
    }
    // flush tail (< 64 entries)
    __builtin_amdgcn_wave_barrier();
    if ((unsigned)lane < qn) {
        uint2 rc = wq[(qhead + lane) & (QCAP - 1)];
        process_edge(rc.x, rc.y, base, nloc, pos, acc);
    }
    __syncthreads();

    for (unsigned i = threadIdx.x; i < nloc * 3; i += NTHR)
        du[base * 3 + i] = acc[i];
}

// ---------------------------------------------------------------------------
// Kernel 2: angular_info[n][:] = ||du[n]||^2, 32 lanes per node.
// ---------------------------------------------------------------------------
__global__ void angular_kernel(const float* __restrict__ du,
                               float* __restrict__ ang) {
    int gid = blockIdx.x * blockDim.x + threadIdx.x;
    int node = gid >> 5;
    int c4   = gid & 31;
    float x = du[node * 3 + 0];
    float y = du[node * 3 + 1];
    float z = du[node * 3 + 2];
    float a = x * x + y * y + z * z;
    vfloat4 v4 = {a, a, a, a};
    __builtin_nontemporal_store(v4,
        reinterpret_cast<vfloat4*>(ang + (size_t)node * HIDDEN) + c4);
}

// ---------------------------------------------------------------------------
// Kernel 3: per-edge dihedral scalar -> broadcast 128-wide row (unchanged).
// ---------------------------------------------------------------------------
__global__ void dihedral_kernel(const float* __restrict__ pos,
                                const int* __restrict__ eidx,
                                const float* __restrict__ du,
                                float* __restrict__ dih) {
    __shared__ float vals[256];
    const int e0 = blockIdx.x * 256;
    const int e  = e0 + threadIdx.x;

    {
        int r = eidx[e];
        int c = eidx[N_EDGES + e];

        float dx = pos[c * 3 + 0] - pos[r * 3 + 0];
        float dy = pos[c * 3 + 1] - pos[r * 3 + 1];
        float dz = pos[c * 3 + 2] - pos[r * 3 + 2];
        float dist = sqrtf(dx * dx + dy * dy + dz * dz) + 1e-8f;
        float inv = 1.0f / dist;
        float ux = dx * inv, uy = dy * inv, uz = dz * inv;

        float vix = du[r * 3 + 0], viy = du[r * 3 + 1], viz = du[r * 3 + 2];
        float vjx = du[c * 3 + 0], vjy = du[c * 3 + 1], vjz = du[c * 3 + 2];

        float dvi = vix * ux + viy * uy + viz * uz;
        float dvj = -(vjx * ux + vjy * uy + vjz * uz);

        float wix = vix - dvi * ux;
        float wiy = viy - dvi * uy;
        float wiz = viz - dvi * uz;
        float wjx = vjx + dvj * ux;
        float wjy = vjy + dvj * uy;
        float wjz = vjz + dvj * uz;

        vals[threadIdx.x] = wix * wjx + wiy * wjy + wiz * wjz;
    }
    __syncthreads();

    vfloat4* out = reinterpret_cast<vfloat4*>(dih + (size_t)e0 * HIDDEN);
    #pragma unroll
    for (int it = 0; it < 32; ++it) {
        int i = it * 256 + threadIdx.x;   // 0 .. 8191
        float v = vals[i >> 5];
        vfloat4 v4 = {v, v, v, v};
        __builtin_nontemporal_store(v4, out + i);
    }
}

// ---------------------------------------------------------------------------
extern "C" void kernel_launch(void* const* d_in, const int* in_sizes, int n_in,
                              void* d_out, int out_size, void* d_ws, size_t ws_size,
                              hipStream_t stream) {
    const float* pos  = (const float*)d_in[0];
    const int*   eidx = (const int*)d_in[1];

    float* out = (float*)d_out;
    float* ang = out;                                         // (N, 128)
    float* dih = out + (size_t)N_NODES * HIDDEN;              // (E, 128)
    float* du  = dih + (size_t)N_EDGES * HIDDEN;              // (N, 3)

    du_range_kernel<<<NBLK, NTHR, 0, stream>>>(pos, eidx, du);

    angular_kernel<<<(N_NODES * 32) / 256, 256, 0, stream>>>(du, ang);

    dihedral_kernel<<<N_EDGES / 256, 256, 0, stream>>>(pos, eidx, du, dih);
}

// Round 5
// 263.211 us; speedup vs baseline: 2.9408x; 2.9408x over previous
//
#include <hip/hip_runtime.h>
#include <math.h>

#define N_NODES 100000
#define N_EDGES 1600000
#define HIDDEN 128

// ---- binning geometry ------------------------------------------------------
#define NBINS      256
#define BIN_NODES  391        // 256*391 = 100096 >= 100000
#define BIN_CAP    16384      // records/bin: mean 12512, sigma ~112 -> +34s
#define A_THREADS  1024
#define A_EPT      2          // edges per thread in phase A
#define A_EPB      (A_THREADS * A_EPT)                    // 2048 edges/block
#define A_BLOCKS   ((N_EDGES + A_EPB - 1) / A_EPB)        // 782
#define B_THREADS  1024

// Native 4-wide float vector — required for __builtin_nontemporal_store.
typedef float vfloat4 __attribute__((ext_vector_type(4)));

// ---------------------------------------------------------------------------
// Kernel A0: zero the 256 bin cursors (d_ws is poisoned, re-zero every call).
// ---------------------------------------------------------------------------
__global__ void zero_cursors_kernel(unsigned* __restrict__ cur) {
    cur[threadIdx.x] = 0u;
}

// ---------------------------------------------------------------------------
// Kernel A: bin edges. Each edge emits 2 records: (e<<1) into bin(row) and
// (e<<1)|1 into bin(col). Per-block LDS counts -> one global cursor atomicAdd
// per (block,bin) -> records land contiguously per bin. ~200K int atomics
// total (vs 9.6M fp32 atomics in the scatter this replaces).
// ---------------------------------------------------------------------------
__global__ __launch_bounds__(A_THREADS) void bin_edges_kernel(
    const int* __restrict__ eidx,
    unsigned* __restrict__ cursors,
    unsigned* __restrict__ region)
{
    __shared__ unsigned cnt[NBINS];
    __shared__ unsigned base[NBINS];
    if (threadIdx.x < NBINS) cnt[threadIdx.x] = 0u;
    __syncthreads();

    const int e0 = blockIdx.x * A_EPB + threadIdx.x;

    // All arrays indexed by compile-time k (full unroll) -> stay in VGPRs.
    bool     val[A_EPT];
    unsigned br[A_EPT], orow[A_EPT], bc[A_EPT], ocol[A_EPT];

    #pragma unroll
    for (int k = 0; k < A_EPT; ++k) {
        int e = e0 + k * A_THREADS;
        val[k] = (e < N_EDGES);
        if (val[k]) {
            unsigned r = (unsigned)eidx[e];
            unsigned c = (unsigned)eidx[N_EDGES + e];
            br[k] = r / BIN_NODES;
            bc[k] = c / BIN_NODES;
            orow[k] = atomicAdd(&cnt[br[k]], 1u);
            ocol[k] = atomicAdd(&cnt[bc[k]], 1u);
        }
    }
    __syncthreads();

    if (threadIdx.x < NBINS)
        base[threadIdx.x] = atomicAdd(&cursors[threadIdx.x], cnt[threadIdx.x]);
    __syncthreads();

    #pragma unroll
    for (int k = 0; k < A_EPT; ++k) {
        if (val[k]) {
            unsigned e = (unsigned)(e0 + k * A_THREADS);
            region[br[k] * BIN_CAP + base[br[k]] + orow[k]] = (e << 1);
            region[bc[k] * BIN_CAP + base[bc[k]] + ocol[k]] = (e << 1) | 1u;
        }
    }
}

// ---------------------------------------------------------------------------
// Kernel B: one block per bin. Read the bin's contiguous records, recompute
// the unit vector (eidx/pos are L2/L3-hot), accumulate du in LDS (no global
// atomics), then write the du slice coalesced and the fused angular rows.
// ---------------------------------------------------------------------------
__global__ __launch_bounds__(B_THREADS) void accumulate_kernel(
    const float* __restrict__ pos,
    const int* __restrict__ eidx,
    const unsigned* __restrict__ cursors,
    const unsigned* __restrict__ region,
    float* __restrict__ du,
    float* __restrict__ ang)
{
    __shared__ float acc[BIN_NODES * 3];    // 4692 B
    const unsigned b = blockIdx.x;
    const unsigned nodebase = b * BIN_NODES;

    for (int i = threadIdx.x; i < BIN_NODES * 3; i += B_THREADS) acc[i] = 0.0f;
    __syncthreads();

    const unsigned n = cursors[b];
    const unsigned* __restrict__ reg = region + (size_t)b * BIN_CAP;

    for (unsigned i = threadIdx.x; i < n; i += B_THREADS) {
        unsigned rec  = reg[i];
        unsigned e    = rec >> 1;
        unsigned side = rec & 1u;
        unsigned r = (unsigned)eidx[e];
        unsigned c = (unsigned)eidx[N_EDGES + e];

        float dx = pos[c * 3 + 0] - pos[r * 3 + 0];
        float dy = pos[c * 3 + 1] - pos[r * 3 + 1];
        float dz = pos[c * 3 + 2] - pos[r * 3 + 2];
        float inv = 1.0f / (sqrtf(dx * dx + dy * dy + dz * dz) + 1e-8f);
        float ux = dx * inv, uy = dy * inv, uz = dz * inv;

        unsigned node = side ? c : r;
        float s = side ? -1.0f : 1.0f;
        unsigned l = node - nodebase;
        atomicAdd(&acc[l * 3 + 0], s * ux);
        atomicAdd(&acc[l * 3 + 1], s * uy);
        atomicAdd(&acc[l * 3 + 2], s * uz);
    }
    __syncthreads();

    const unsigned nloc = min((unsigned)BIN_NODES,
                              (unsigned)(N_NODES - nodebase));

    for (unsigned i = threadIdx.x; i < nloc * 3; i += B_THREADS)
        du[(size_t)nodebase * 3 + i] = acc[i];

    for (unsigned j = threadIdx.x; j < nloc * 32; j += B_THREADS) {
        unsigned node = j >> 5, c4 = j & 31;
        float x = acc[node * 3 + 0];
        float y = acc[node * 3 + 1];
        float z = acc[node * 3 + 2];
        float a = x * x + y * y + z * z;
        vfloat4 v4 = {a, a, a, a};
        __builtin_nontemporal_store(v4,
            reinterpret_cast<vfloat4*>(ang + (size_t)(nodebase + node) * HIDDEN) + c4);
    }
}

// ---------------------------------------------------------------------------
// Kernel C: per-edge dihedral scalar -> broadcast 128-wide row (unchanged).
// ---------------------------------------------------------------------------
__global__ void dihedral_kernel(const float* __restrict__ pos,
                                const int* __restrict__ eidx,
                                const float* __restrict__ du,
                                float* __restrict__ dih) {
    __shared__ float vals[256];
    const int e0 = blockIdx.x * 256;
    const int e  = e0 + threadIdx.x;

    {
        int r = eidx[e];
        int c = eidx[N_EDGES + e];

        float dx = pos[c * 3 + 0] - pos[r * 3 + 0];
        float dy = pos[c * 3 + 1] - pos[r * 3 + 1];
        float dz = pos[c * 3 + 2] - pos[r * 3 + 2];
        float dist = sqrtf(dx * dx + dy * dy + dz * dz) + 1e-8f;
        float inv = 1.0f / dist;
        float ux = dx * inv, uy = dy * inv, uz = dz * inv;

        float vix = du[r * 3 + 0], viy = du[r * 3 + 1], viz = du[r * 3 + 2];
        float vjx = du[c * 3 + 0], vjy = du[c * 3 + 1], vjz = du[c * 3 + 2];

        float dvi = vix * ux + viy * uy + viz * uz;
        float dvj = -(vjx * ux + vjy * uy + vjz * uz);

        float wix = vix - dvi * ux;
        float wiy = viy - dvi * uy;
        float wiz = viz - dvi * uz;
        float wjx = vjx + dvj * ux;
        float wjy = vjy + dvj * uy;
        float wjz = vjz + dvj * uz;

        vals[threadIdx.x] = wix * wjx + wiy * wjy + wiz * wjz;
    }
    __syncthreads();

    vfloat4* out = reinterpret_cast<vfloat4*>(dih + (size_t)e0 * HIDDEN);
    #pragma unroll
    for (int it = 0; it < 32; ++it) {
        int i = it * 256 + threadIdx.x;   // 0 .. 8191
        float v = vals[i >> 5];
        vfloat4 v4 = {v, v, v, v};
        __builtin_nontemporal_store(v4, out + i);
    }
}

// ---------------------------------------------------------------------------
// Fallback path (ws too small): R3-style direct global-atomic scatter.
// ---------------------------------------------------------------------------
__global__ void zero_du_kernel(float* __restrict__ du, int n) {
    int i = blockIdx.x * blockDim.x + threadIdx.x;
    if (i < n) du[i] = 0.0f;
}

__global__ void edge_scatter_kernel(const float* __restrict__ pos,
                                    const int* __restrict__ eidx,
                                    float* __restrict__ du) {
    int e = blockIdx.x * blockDim.x + threadIdx.x;
    if (e >= N_EDGES) return;
    int r = eidx[e];
    int c = eidx[N_EDGES + e];
    float dx = pos[c * 3 + 0] - pos[r * 3 + 0];
    float dy = pos[c * 3 + 1] - pos[r * 3 + 1];
    float dz = pos[c * 3 + 2] - pos[r * 3 + 2];
    float inv = 1.0f / (sqrtf(dx * dx + dy * dy + dz * dz) + 1e-8f);
    float ux = dx * inv, uy = dy * inv, uz = dz * inv;
    atomicAdd(&du[r * 3 + 0],  ux);
    atomicAdd(&du[r * 3 + 1],  uy);
    atomicAdd(&du[r * 3 + 2],  uz);
    atomicAdd(&du[c * 3 + 0], -ux);
    atomicAdd(&du[c * 3 + 1], -uy);
    atomicAdd(&du[c * 3 + 2], -uz);
}

__global__ void angular_kernel(const float* __restrict__ du,
                               float* __restrict__ ang) {
    int gid = blockIdx.x * blockDim.x + threadIdx.x;
    int node = gid >> 5;
    int c4   = gid & 31;
    float x = du[node * 3 + 0];
    float y = du[node * 3 + 1];
    float z = du[node * 3 + 2];
    float a = x * x + y * y + z * z;
    vfloat4 v4 = {a, a, a, a};
    __builtin_nontemporal_store(v4,
        reinterpret_cast<vfloat4*>(ang + (size_t)node * HIDDEN) + c4);
}

// ---------------------------------------------------------------------------
extern "C" void kernel_launch(void* const* d_in, const int* in_sizes, int n_in,
                              void* d_out, int out_size, void* d_ws, size_t ws_size,
                              hipStream_t stream) {
    const float* pos  = (const float*)d_in[0];
    const int*   eidx = (const int*)d_in[1];

    float* out = (float*)d_out;
    float* ang = out;                                         // (N, 128)
    float* dih = out + (size_t)N_NODES * HIDDEN;              // (E, 128)
    float* du  = dih + (size_t)N_EDGES * HIDDEN;              // (N, 3)

    const size_t need = 1024 + (size_t)NBINS * BIN_CAP * sizeof(unsigned);

    if (ws_size >= need) {
        unsigned* cursors = (unsigned*)d_ws;                  // 256 u32
        unsigned* region  = (unsigned*)d_ws + 256;            // bin regions

        zero_cursors_kernel<<<1, NBINS, 0, stream>>>(cursors);
        bin_edges_kernel<<<A_BLOCKS, A_THREADS, 0, stream>>>(eidx, cursors, region);
        accumulate_kernel<<<NBINS, B_THREADS, 0, stream>>>(pos, eidx, cursors,
                                                           region, du, ang);
    } else {
        zero_du_kernel<<<(N_NODES * 3 + 255) / 256, 256, 0, stream>>>(du, N_NODES * 3);
        edge_scatter_kernel<<<(N_EDGES + 255) / 256, 256, 0, stream>>>(pos, eidx, du);
        angular_kernel<<<(N_NODES * 32) / 256, 256, 0, stream>>>(du, ang);
    }

    dihedral_kernel<<<N_EDGES / 256, 256, 0, stream>>>(pos, eidx, du, dih);
}

// Round 6
// 256.588 us; speedup vs baseline: 3.0167x; 1.0258x over previous
//
#include <hip/hip_runtime.h>
#include <math.h>

#define N_NODES 100000
#define N_EDGES 1600000
#define HIDDEN 128

// ---- binning geometry ------------------------------------------------------
#define NBINS      256
#define BIN_NODES  391        // 256*391 = 100096 >= 100000
#define BIN_CAP    16384      // records/bin: mean 12512, sigma ~112
#define A_THREADS  1024
#define A_EPT      2          // edges per thread (int2-vectorized)
#define A_EPB      (A_THREADS * A_EPT)                    // 2048 edges/block
#define A_BLOCKS   ((N_EDGES + A_EPB - 1) / A_EPB)        // 782
#define B_THREADS  1024

// Record layout: [26:17]=own-local node (9b), [16:0]=other node id (17b).
// Sign trick: row gets +u = normalize(pos[col]-pos[row]); col gets -u =
// normalize(pos[row]-pos[col]). Both are normalize(pos[other]-pos[own]),
// so no side/sign bit is needed and phase B never touches eidx.

// Native 4-wide float vector — required for __builtin_nontemporal_store.
typedef float vfloat4 __attribute__((ext_vector_type(4)));

// ---------------------------------------------------------------------------
// Kernel A0: zero the 256 bin cursors (d_ws is poisoned once before timing).
// ---------------------------------------------------------------------------
__global__ void zero_cursors_kernel(unsigned* __restrict__ cur) {
    cur[threadIdx.x] = 0u;
}

// ---------------------------------------------------------------------------
// Kernel A: bin edges. Each edge emits a record into bin(row) and bin(col).
// Per-block LDS counts -> one global cursor atomicAdd per (block,bin).
// ---------------------------------------------------------------------------
__global__ __launch_bounds__(A_THREADS) void bin_edges_kernel(
    const int* __restrict__ eidx,
    unsigned* __restrict__ cursors,
    unsigned* __restrict__ region)
{
    __shared__ unsigned cnt[NBINS];
    __shared__ unsigned base[NBINS];
    if (threadIdx.x < NBINS) cnt[threadIdx.x] = 0u;
    __syncthreads();

    const int e0 = blockIdx.x * A_EPB + threadIdx.x * 2;
    const bool valid = (e0 < N_EDGES);   // N_EDGES even -> e0+1 also valid

    unsigned r[A_EPT], c[A_EPT], br[A_EPT], bc[A_EPT], orow[A_EPT], ocol[A_EPT];

    if (valid) {
        int2 rr = *reinterpret_cast<const int2*>(eidx + e0);
        int2 cc = *reinterpret_cast<const int2*>(eidx + N_EDGES + e0);
        r[0] = (unsigned)rr.x; r[1] = (unsigned)rr.y;
        c[0] = (unsigned)cc.x; c[1] = (unsigned)cc.y;
        #pragma unroll
        for (int k = 0; k < A_EPT; ++k) {
            br[k] = r[k] / BIN_NODES;
            bc[k] = c[k] / BIN_NODES;
            orow[k] = atomicAdd(&cnt[br[k]], 1u);
            ocol[k] = atomicAdd(&cnt[bc[k]], 1u);
        }
    }
    __syncthreads();

    if (threadIdx.x < NBINS)
        base[threadIdx.x] = atomicAdd(&cursors[threadIdx.x], cnt[threadIdx.x]);
    __syncthreads();

    if (valid) {
        #pragma unroll
        for (int k = 0; k < A_EPT; ++k) {
            region[br[k] * BIN_CAP + base[br[k]] + orow[k]] =
                ((r[k] - br[k] * BIN_NODES) << 17) | c[k];
            region[bc[k] * BIN_CAP + base[bc[k]] + ocol[k]] =
                ((c[k] - bc[k] * BIN_NODES) << 17) | r[k];
        }
    }
}

// ---------------------------------------------------------------------------
// Kernel B: one block per bin. Coalesced uint4 record loads; own-pos from an
// LDS stage, other-pos from L2-resident pos; accumulate du in LDS; write du
// slice + fused angular rows. No eidx access at all.
// ---------------------------------------------------------------------------
__device__ __forceinline__ void proc_rec(unsigned rec,
                                         const float* __restrict__ posLDS,
                                         const float* __restrict__ pos,
                                         float* __restrict__ acc) {
    unsigned other = rec & 0x1FFFFu;
    unsigned local = rec >> 17;
    float sx = posLDS[local * 3 + 0];
    float sy = posLDS[local * 3 + 1];
    float sz = posLDS[local * 3 + 2];
    float dx = pos[other * 3 + 0] - sx;
    float dy = pos[other * 3 + 1] - sy;
    float dz = pos[other * 3 + 2] - sz;
    float inv = 1.0f / (sqrtf(dx * dx + dy * dy + dz * dz) + 1e-8f);
    atomicAdd(&acc[local * 3 + 0], dx * inv);
    atomicAdd(&acc[local * 3 + 1], dy * inv);
    atomicAdd(&acc[local * 3 + 2], dz * inv);
}

__global__ __launch_bounds__(B_THREADS) void accumulate_kernel(
    const float* __restrict__ pos,
    const unsigned* __restrict__ cursors,
    const unsigned* __restrict__ region,
    float* __restrict__ du,
    float* __restrict__ ang)
{
    __shared__ float acc[BIN_NODES * 3];     // 4692 B
    __shared__ float posLDS[BIN_NODES * 3];  // 4692 B
    const unsigned b = blockIdx.x;
    const unsigned nodebase = b * BIN_NODES;
    const unsigned nloc = min((unsigned)BIN_NODES,
                              (unsigned)(N_NODES - nodebase));

    for (int i = threadIdx.x; i < BIN_NODES * 3; i += B_THREADS) acc[i] = 0.0f;
    for (unsigned i = threadIdx.x; i < nloc * 3; i += B_THREADS)
        posLDS[i] = pos[(size_t)nodebase * 3 + i];
    __syncthreads();

    const unsigned n = cursors[b];
    const unsigned* __restrict__ reg = region + (size_t)b * BIN_CAP;
    const unsigned n4 = n & ~3u;

    for (unsigned i = threadIdx.x * 4; i < n4; i += B_THREADS * 4) {
        uint4 rc = *reinterpret_cast<const uint4*>(reg + i);
        proc_rec(rc.x, posLDS, pos, acc);
        proc_rec(rc.y, posLDS, pos, acc);
        proc_rec(rc.z, posLDS, pos, acc);
        proc_rec(rc.w, posLDS, pos, acc);
    }
    for (unsigned i = n4 + threadIdx.x; i < n; i += B_THREADS)
        proc_rec(reg[i], posLDS, pos, acc);
    __syncthreads();

    for (unsigned i = threadIdx.x; i < nloc * 3; i += B_THREADS)
        du[(size_t)nodebase * 3 + i] = acc[i];

    for (unsigned j = threadIdx.x; j < nloc * 32; j += B_THREADS) {
        unsigned node = j >> 5, c4 = j & 31;
        float x = acc[node * 3 + 0];
        float y = acc[node * 3 + 1];
        float z = acc[node * 3 + 2];
        float a = x * x + y * y + z * z;
        vfloat4 v4 = {a, a, a, a};
        __builtin_nontemporal_store(v4,
            reinterpret_cast<vfloat4*>(ang + (size_t)(nodebase + node) * HIDDEN) + c4);
    }
}

// ---------------------------------------------------------------------------
// Kernel C: per-edge dihedral scalar -> broadcast 128-wide row (unchanged).
// ---------------------------------------------------------------------------
__global__ void dihedral_kernel(const float* __restrict__ pos,
                                const int* __restrict__ eidx,
                                const float* __restrict__ du,
                                float* __restrict__ dih) {
    __shared__ float vals[256];
    const int e0 = blockIdx.x * 256;
    const int e  = e0 + threadIdx.x;

    {
        int r = eidx[e];
        int c = eidx[N_EDGES + e];

        float dx = pos[c * 3 + 0] - pos[r * 3 + 0];
        float dy = pos[c * 3 + 1] - pos[r * 3 + 1];
        float dz = pos[c * 3 + 2] - pos[r * 3 + 2];
        float dist = sqrtf(dx * dx + dy * dy + dz * dz) + 1e-8f;
        float inv = 1.0f / dist;
        float ux = dx * inv, uy = dy * inv, uz = dz * inv;

        float vix = du[r * 3 + 0], viy = du[r * 3 + 1], viz = du[r * 3 + 2];
        float vjx = du[c * 3 + 0], vjy = du[c * 3 + 1], vjz = du[c * 3 + 2];

        float dvi = vix * ux + viy * uy + viz * uz;
        float dvj = -(vjx * ux + vjy * uy + vjz * uz);

        float wix = vix - dvi * ux;
        float wiy = viy - dvi * uy;
        float wiz = viz - dvi * uz;
        float wjx = vjx + dvj * ux;
        float wjy = vjy + dvj * uy;
        float wjz = vjz + dvj * uz;

        vals[threadIdx.x] = wix * wjx + wiy * wjy + wiz * wjz;
    }
    __syncthreads();

    vfloat4* out = reinterpret_cast<vfloat4*>(dih + (size_t)e0 * HIDDEN);
    #pragma unroll
    for (int it = 0; it < 32; ++it) {
        int i = it * 256 + threadIdx.x;   // 0 .. 8191
        float v = vals[i >> 5];
        vfloat4 v4 = {v, v, v, v};
        __builtin_nontemporal_store(v4, out + i);
    }
}

// ---------------------------------------------------------------------------
// Fallback path (ws too small): R3-style direct global-atomic scatter.
// ---------------------------------------------------------------------------
__global__ void zero_du_kernel(float* __restrict__ du, int n) {
    int i = blockIdx.x * blockDim.x + threadIdx.x;
    if (i < n) du[i] = 0.0f;
}

__global__ void edge_scatter_kernel(const float* __restrict__ pos,
                                    const int* __restrict__ eidx,
                                    float* __restrict__ du) {
    int e = blockIdx.x * blockDim.x + threadIdx.x;
    if (e >= N_EDGES) return;
    int r = eidx[e];
    int c = eidx[N_EDGES + e];
    float dx = pos[c * 3 + 0] - pos[r * 3 + 0];
    float dy = pos[c * 3 + 1] - pos[r * 3 + 1];
    float dz = pos[c * 3 + 2] - pos[r * 3 + 2];
    float inv = 1.0f / (sqrtf(dx * dx + dy * dy + dz * dz) + 1e-8f);
    float ux = dx * inv, uy = dy * inv, uz = dz * inv;
    atomicAdd(&du[r * 3 + 0],  ux);
    atomicAdd(&du[r * 3 + 1],  uy);
    atomicAdd(&du[r * 3 + 2],  uz);
    atomicAdd(&du[c * 3 + 0], -ux);
    atomicAdd(&du[c * 3 + 1], -uy);
    atomicAdd(&du[c * 3 + 2], -uz);
}

__global__ void angular_kernel(const float* __restrict__ du,
                               float* __restrict__ ang) {
    int gid = blockIdx.x * blockDim.x + threadIdx.x;
    int node = gid >> 5;
    int c4   = gid & 31;
    float x = du[node * 3 + 0];
    float y = du[node * 3 + 1];
    float z = du[node * 3 + 2];
    float a = x * x + y * y + z * z;
    vfloat4 v4 = {a, a, a, a};
    __builtin_nontemporal_store(v4,
        reinterpret_cast<vfloat4*>(ang + (size_t)node * HIDDEN) + c4);
}

// ---------------------------------------------------------------------------
extern "C" void kernel_launch(void* const* d_in, const int* in_sizes, int n_in,
                              void* d_out, int out_size, void* d_ws, size_t ws_size,
                              hipStream_t stream) {
    const float* pos  = (const float*)d_in[0];
    const int*   eidx = (const int*)d_in[1];

    float* out = (float*)d_out;
    float* ang = out;                                         // (N, 128)
    float* dih = out + (size_t)N_NODES * HIDDEN;              // (E, 128)
    float* du  = dih + (size_t)N_EDGES * HIDDEN;              // (N, 3)

    const size_t need = 1024 + (size_t)NBINS * BIN_CAP * sizeof(unsigned);

    if (ws_size >= need) {
        unsigned* cursors = (unsigned*)d_ws;                  // 256 u32
        unsigned* region  = (unsigned*)d_ws + 256;            // bin regions

        zero_cursors_kernel<<<1, NBINS, 0, stream>>>(cursors);
        bin_edges_kernel<<<A_BLOCKS, A_THREADS, 0, stream>>>(eidx, cursors, region);
        accumulate_kernel<<<NBINS, B_THREADS, 0, stream>>>(pos, cursors,
                                                           region, du, ang);
    } else {
        zero_du_kernel<<<(N_NODES * 3 + 255) / 256, 256, 0, stream>>>(du, N_NODES * 3);
        edge_scatter_kernel<<<(N_EDGES + 255) / 256, 256, 0, stream>>>(pos, eidx, du);
        angular_kernel<<<(N_NODES * 32) / 256, 256, 0, stream>>>(du, ang);
    }

    dihedral_kernel<<<N_EDGES / 256, 256, 0, stream>>>(pos, eidx, du, dih);
}